// Round 4
// baseline (408.029 us; speedup 1.0000x reference)
//
#include <hip/hip_runtime.h>

#define B_SZ 2048
#define OBS_DIM 4096
#define N_GVFS 4096
#define IPG 16
#define HPG 8
#define N_ACT 18
#define TOTAL_FEAT (OBS_DIM + HPG * N_GVFS) /* 36864 */

#define BT 8                  /* batch rows per block */
#define NTHREADS 1024
#define RPT 2                 /* rows per thread  (fits the 128-VGPR budget) */
#define NGRP (BT / RPT)       /* 4 row-groups */
#define TPG (NTHREADS / NGRP) /* 256 threads per group */
#define GPT (N_GVFS / TPG)    /* 16 gvfs per thread */

// Column-block permute: XOR j's bits 2-3 into the LDS block index (addr bits
// 5-6). Bijective. Phase-A scalar writes become exactly 2-way (free, m136);
// verified round 3 (residual conflicts are the random Phase-B gathers).
__device__ __forceinline__ int col_block(int j) { return j ^ ((j >> 2) & 3); }

// ---------------------------------------------------------------------------
// Pre-kernel: transpose gvf_W [g][h][i] -> Wt [g][i][h] so stage-1 reads of
// "all h for one i" are contiguous (2 x float4).
// ---------------------------------------------------------------------------
__global__ void wt_transpose_kernel(const float* __restrict__ W,
                                    float* __restrict__ Wt) {
    const int g = blockIdx.x;
    const int e = threadIdx.x; // 0..127 ; e = h*16 + i
    const float v = W[g * 128 + e];
    const int h = e >> 4;
    const int i = e & 15;
    Wt[g * 128 + i * 8 + h] = v;
}

// ---------------------------------------------------------------------------
// Fused kernel: one block = 8 batch rows; 1024 threads = 4 row-groups x 256.
//  Rounds 1-3 lesson: the allocator pins VGPRs at 128 (4-waves/EU budget)
//  no matter what __launch_bounds__ says -> design under 128:
//  per-thread state qacc[2][18]+v[2][8]+jv[16]+qh[8] ~= 105 VGPRs, no spill.
//  1024 threads = 16 waves/CU = 4 waves/SIMD (2x round 3's latency hiding).
//  Phase A: obs tile -> LDS column-major (col j = 8 rows = 32 B), block-
//           permuted + half-swizzled; writes 2-way conflict-free.
//  Phase B: per thread: 16 gvfs x 2 rows; b64 gather of its 2 rows, 16->8
//           relu MLP, fold into qacc[2][18] with q_W gvf columns.
//  Phase C: obs part of the Q head.
//  Phase D: wave shuffle-reduce (all indices compile-time) -> 144 outputs.
// ---------------------------------------------------------------------------
template <int WT_MODE>
__global__ __launch_bounds__(NTHREADS)
void fused_gvf_q_kernel(const float* __restrict__ obs,
                        const float* __restrict__ Wt,   // [g][i][h] if WT_MODE else [g][h][i]
                        const float* __restrict__ qW,   // [a][36864]
                        const int*   __restrict__ gidx, // [g][16]
                        float* __restrict__ out)        // [b][18]
{
    __shared__ __align__(16) float smem[OBS_DIM * BT]; // 128 KiB
    __shared__ float red2[16][RPT][N_ACT];             // per-wave partials

    const int tid = threadIdx.x;
    const int b0  = blockIdx.x * BT;
    char* const smem_b = (char*)smem;

    // ---------------- Phase A: obs tile -> LDS (column-major, swizzled) ----
    for (int m = 0; m < 8; ++m) {
        const int id  = tid + NTHREADS * m;   // float4 id over the tile
        const int row = id & 7;
        const int j4  = id >> 3;              // 0..1023
        const float4 v4 = *(const float4*)(obs + (size_t)(b0 + row) * OBS_DIM + j4 * 4);
        const float vv[4] = {v4.x, v4.y, v4.z, v4.w};
#pragma unroll
        for (int c = 0; c < 4; ++c) {
            const int j   = j4 * 4 + c;
            const int blk = col_block(j);
            const int byteoff = (blk << 5) + ((((row >> 2) ^ (j & 1)) & 1) << 4) + ((row & 3) << 2);
            *(float*)(smem_b + byteoff) = vv[c];
        }
    }
    __syncthreads();

    const int h  = tid >> 8;   // row-group 0..3: rows {2h, 2h+1}
    const int tg = tid & (TPG - 1);

    // Read addressing for this group's 2 rows within a column:
    //   16-B half  = (row>>2) ^ (j&1) = (h>>1) ^ (j&1)
    //   8-B offset within half = (h&1)*8   (rows 2h,2h+1 are adjacent floats)
    const int h_hi = h >> 1;
    const int h_lo8 = (h & 1) << 3;

    float qacc[RPT][N_ACT];
#pragma unroll
    for (int r = 0; r < RPT; ++r)
#pragma unroll
        for (int a = 0; a < N_ACT; ++a) qacc[r][a] = 0.f;

    // ---------------- Phase B: GVF MLP + Q-head gvf part -------------------
#pragma unroll 1
    for (int k = 0; k < GPT; ++k) {
        const int g = tg + TPG * k;
        const float* wg = Wt + (size_t)g * (IPG * HPG);
        const float* qg = qW + OBS_DIM + (size_t)g * HPG;

        int jv[IPG];
        {
            const int4* gi4 = (const int4*)(gidx + g * IPG);
#pragma unroll
            for (int q = 0; q < 4; ++q) {
                const int4 t4 = gi4[q];
                jv[q * 4 + 0] = t4.x; jv[q * 4 + 1] = t4.y;
                jv[q * 4 + 2] = t4.z; jv[q * 4 + 3] = t4.w;
            }
        }

        float v[RPT][HPG];
#pragma unroll
        for (int r = 0; r < RPT; ++r)
#pragma unroll
            for (int hh = 0; hh < HPG; ++hh) v[r][hh] = 0.f;

#pragma unroll
        for (int i = 0; i < IPG; ++i) {
            const int j   = jv[i];
            const int off = (col_block(j) << 5) + (((h_hi ^ j) & 1) << 4) + h_lo8;
            const float2 x2 = *(const float2*)(smem_b + off);
            float w[HPG];
            if constexpr (WT_MODE) {
                const float4 w0 = *(const float4*)(wg + i * 8);
                const float4 w1 = *(const float4*)(wg + i * 8 + 4);
                w[0]=w0.x; w[1]=w0.y; w[2]=w0.z; w[3]=w0.w;
                w[4]=w1.x; w[5]=w1.y; w[6]=w1.z; w[7]=w1.w;
            } else {
#pragma unroll
                for (int hh = 0; hh < HPG; ++hh) w[hh] = wg[hh * IPG + i];
            }
#pragma unroll
            for (int hh = 0; hh < HPG; ++hh) {
                v[0][hh] = fmaf(x2.x, w[hh], v[0][hh]);
                v[1][hh] = fmaf(x2.y, w[hh], v[1][hh]);
            }
        }
        // relu
#pragma unroll
        for (int r = 0; r < RPT; ++r)
#pragma unroll
            for (int hh = 0; hh < HPG; ++hh) v[r][hh] = fmaxf(v[r][hh], 0.f);

        // q head, gvf columns: qacc[r][a] += sum_h v[r][h] * qW[a][4096+g*8+h]
#pragma unroll
        for (int a = 0; a < N_ACT; ++a) {
            const float4 q0 = *(const float4*)(qg + (size_t)a * TOTAL_FEAT);
            const float4 q1 = *(const float4*)(qg + (size_t)a * TOTAL_FEAT + 4);
            const float qh[HPG] = {q0.x, q0.y, q0.z, q0.w, q1.x, q1.y, q1.z, q1.w};
            float acc0 = qacc[0][a], acc1 = qacc[1][a];
#pragma unroll
            for (int hh = 0; hh < HPG; ++hh) {
                acc0 = fmaf(v[0][hh], qh[hh], acc0);
                acc1 = fmaf(v[1][hh], qh[hh], acc1);
            }
            qacc[0][a] = acc0; qacc[1][a] = acc1;
        }
    }

    // ---------------- Phase C: Q-head obs part -----------------------------
#pragma unroll 1
    for (int jj = 0; jj < OBS_DIM / TPG; ++jj) { // 16
        const int j   = tg + TPG * jj;
        const int off = (col_block(j) << 5) + (((h_hi ^ j) & 1) << 4) + h_lo8;
        const float2 x2 = *(const float2*)(smem_b + off);
#pragma unroll
        for (int a = 0; a < N_ACT; ++a) {
            const float qc = qW[(size_t)a * TOTAL_FEAT + j];
            qacc[0][a] = fmaf(qc, x2.x, qacc[0][a]);
            qacc[1][a] = fmaf(qc, x2.y, qacc[1][a]);
        }
    }

    // ---------------- Phase D: wave shuffle reduce -> 144 outputs ----------
    // Waves 4h..4h+3 belong to row-group h.
    const int wv = tid >> 6;
#pragma unroll
    for (int r = 0; r < RPT; ++r)
#pragma unroll
        for (int a = 0; a < N_ACT; ++a) {
            float s = qacc[r][a];
#pragma unroll
            for (int m = 1; m < 64; m <<= 1)
                s += __shfl_xor(s, m, 64);
            if ((tid & 63) == 0) red2[wv][r][a] = s;
        }
    __syncthreads();
    if (tid < BT * N_ACT) { // 144
        const int row = tid / N_ACT;  // 0..7
        const int a   = tid % N_ACT;
        const int hg  = row >> 1;     // group
        const int r   = row & 1;
        float s = 0.f;
#pragma unroll
        for (int w2 = 0; w2 < 4; ++w2) s += red2[hg * 4 + w2][r][a];
        out[(size_t)(b0 + row) * N_ACT + a] = s;
    }
}

// ---------------------------------------------------------------------------
extern "C" void kernel_launch(void* const* d_in, const int* in_sizes, int n_in,
                              void* d_out, int out_size, void* d_ws, size_t ws_size,
                              hipStream_t stream) {
    const float* obs  = (const float*)d_in[0];
    const float* gvfW = (const float*)d_in[1];
    const float* qW   = (const float*)d_in[2];
    const int*   gidx = (const int*)d_in[3];
    float* out = (float*)d_out;

    const size_t wt_bytes = (size_t)N_GVFS * IPG * HPG * sizeof(float); // 2 MiB
    const dim3 grid(B_SZ / BT), blk(NTHREADS);

    if (ws_size >= wt_bytes) {
        float* wt = (float*)d_ws;
        wt_transpose_kernel<<<dim3(N_GVFS), dim3(128), 0, stream>>>(gvfW, wt);
        fused_gvf_q_kernel<1><<<grid, blk, 0, stream>>>(obs, wt, qW, gidx, out);
    } else {
        fused_gvf_q_kernel<0><<<grid, blk, 0, stream>>>(obs, gvfW, qW, gidx, out);
    }
}

// Round 5
// 224.183 us; speedup vs baseline: 1.8201x; 1.8201x over previous
//
#include <hip/hip_runtime.h>

#define B_SZ 2048
#define OBS_DIM 4096
#define N_GVFS 4096
#define IPG 16
#define HPG 8
#define N_ACT 18
#define TOTAL_FEAT (OBS_DIM + HPG * N_GVFS) /* 36864 */

#define BT 8                 /* batch rows per block */
#define NTHREADS 512         /* 4 row-pair groups x 128 gvf slots */
#define CHUNK 128            /* gvfs staged in LDS per step */
#define NCHUNK (N_GVFS / CHUNK)

/* workspace layout (bytes) */
#define WS_WT 0u             /* bf16 wtT[i][g][h] : 16*4096*8*2 = 1,048,576 */
#define WS_Q 1048576u        /* bf16 qT [a][g][h] : 18*4096*8*2 = 1,179,648 */
#define WS_IDX 2228224u      /* u16  idxT[i][g]   : 16*4096*2   =   131,072 */
#define WS_NEED 2359296u

// ---------------------------------------------------------------------------
__device__ __forceinline__ unsigned short f32_bf16_rne(float f) {
    unsigned int u = __float_as_uint(f);
    u += 0x7FFFu + ((u >> 16) & 1u);
    return (unsigned short)(u >> 16);
}
__device__ __forceinline__ float bf_lo(unsigned int p) { return __uint_as_float(p << 16); }
__device__ __forceinline__ float bf_hi(unsigned int p) { return __uint_as_float(p & 0xFFFF0000u); }

// async global->LDS: LDS dest is wave-uniform base + lane*size (m104);
// global src is per-lane. size must be a literal.
__device__ __forceinline__ void gll16(const void* g, void* l) {
    __builtin_amdgcn_global_load_lds(
        (const __attribute__((address_space(1))) unsigned int*)g,
        (__attribute__((address_space(3))) unsigned int*)l, 16, 0, 0);
}
__device__ __forceinline__ void gll4(const void* g, void* l) {
    __builtin_amdgcn_global_load_lds(
        (const __attribute__((address_space(1))) unsigned int*)g,
        (__attribute__((address_space(3))) unsigned int*)l, 4, 0, 0);
}

// ---------------------------------------------------------------------------
// Pack kernels: build bf16/u16 staged layouts so chunk c's slice of each
// array is CONTIGUOUS (global_load_lds stages linearly) and hot-loop LDS
// reads are linear b128 (lane-consecutive 16-B) => conflict-free.
// ---------------------------------------------------------------------------
__global__ __launch_bounds__(256) void pack_wt_kernel(const float* __restrict__ W,
                                                      unsigned short* __restrict__ dst) {
    const int id = blockIdx.x * 256 + threadIdx.x; // 65536 = 16 i x 4096 g
    const int i = id >> 12, g = id & 4095;
    unsigned int p[4];
#pragma unroll
    for (int hp = 0; hp < 4; ++hp) {
        const float a = W[g * 128 + (2 * hp) * 16 + i];
        const float b = W[g * 128 + (2 * hp + 1) * 16 + i];
        p[hp] = (unsigned int)f32_bf16_rne(a) | ((unsigned int)f32_bf16_rne(b) << 16);
    }
    *(uint4*)(dst + (size_t)(i * 4096 + g) * 8) = make_uint4(p[0], p[1], p[2], p[3]);
}

__global__ __launch_bounds__(256) void pack_q_kernel(const float* __restrict__ qW,
                                                     unsigned short* __restrict__ dst) {
    const int id = blockIdx.x * 256 + threadIdx.x; // 73728 = 18 a x 4096 g
    const int a = id >> 12, g = id & 4095;
    const float* src = qW + (size_t)a * TOTAL_FEAT + OBS_DIM + (size_t)g * 8;
    const float4 f0 = *(const float4*)(src);
    const float4 f1 = *(const float4*)(src + 4);
    unsigned int p0 = (unsigned int)f32_bf16_rne(f0.x) | ((unsigned int)f32_bf16_rne(f0.y) << 16);
    unsigned int p1 = (unsigned int)f32_bf16_rne(f0.z) | ((unsigned int)f32_bf16_rne(f0.w) << 16);
    unsigned int p2 = (unsigned int)f32_bf16_rne(f1.x) | ((unsigned int)f32_bf16_rne(f1.y) << 16);
    unsigned int p3 = (unsigned int)f32_bf16_rne(f1.z) | ((unsigned int)f32_bf16_rne(f1.w) << 16);
    *(uint4*)(dst + (size_t)(a * 4096 + g) * 8) = make_uint4(p0, p1, p2, p3);
}

__global__ __launch_bounds__(256) void pack_idx_kernel(const int* __restrict__ gidx,
                                                       unsigned short* __restrict__ dst) {
    const int id = blockIdx.x * 256 + threadIdx.x; // 65536 = 16 i x 4096 g
    const int i = id >> 12, g = id & 4095;
    dst[(size_t)i * 4096 + g] = (unsigned short)gidx[g * 16 + i];
}

// ---------------------------------------------------------------------------
// Fused kernel. Block = 8 batch rows, 512 threads = 4 row-pair groups x 128
// gvf slots. Per chunk of 128 gvfs: bulk-stage wt/q/idx into LDS ONCE
// (shared by all 4 groups -> kills round 4's 4x redundant per-thread global
// weight streams AND their VGPR-starved latency chains), then compute from
// LDS with linear b128 reads. Accumulation fp32 throughout; phase C (obs
// part of Q head) is pure fp32 from global.
// ---------------------------------------------------------------------------
__global__ __launch_bounds__(NTHREADS)
void fused_kernel(const float* __restrict__ obs,
                  const float* __restrict__ qW,
                  const unsigned char* __restrict__ ws,
                  float* __restrict__ out)
{
    __shared__ __align__(16) unsigned short obs_t[OBS_DIM * BT];       // 65536 B, col-major bf16
    __shared__ __align__(16) unsigned short wt_s[IPG * CHUNK * HPG];   // 32768 B
    __shared__ __align__(16) unsigned short q_s[N_ACT * CHUNK * HPG];  // 36864 B
    __shared__ __align__(16) unsigned short idx_s[IPG * CHUNK];        //  4096 B
    __shared__ float red2[8][2][N_ACT];                                //  1152 B

    const int tid  = threadIdx.x;
    const int b0   = blockIdx.x * BT;
    const int lane = tid & 63;
    const int wv   = tid >> 6;          // wave 0..7
    const int h    = tid >> 7;          // row-pair group 0..3 -> rows 2h,2h+1
    const int s    = tid & (CHUNK - 1); // gvf slot 0..127

    // ---------------- Phase A: obs tile -> LDS bf16 column-major -----------
    // col j occupies 16 B: rows 0..7 as bf16. One b32 read at j*16+4h gives
    // a group's two rows.
    for (int m = 0; m < 16; ++m) {
        const int id  = tid + NTHREADS * m;
        const int row = id & 7;
        const int j4  = id >> 3; // 0..4095
        const float4 v4 = *(const float4*)(obs + (size_t)(b0 + row) * OBS_DIM + j4 * 4);
        const float vv[4] = {v4.x, v4.y, v4.z, v4.w};
        char* base = (char*)obs_t + row * 2;
#pragma unroll
        for (int c = 0; c < 4; ++c)
            *(unsigned short*)(base + (size_t)(j4 * 4 + c) * 16) = f32_bf16_rne(vv[c]);
    }

    float qacc[2][N_ACT];
#pragma unroll
    for (int r = 0; r < 2; ++r)
#pragma unroll
        for (int a = 0; a < N_ACT; ++a) qacc[r][a] = 0.f;

    const unsigned char* wsWt  = ws + WS_WT;
    const unsigned char* wsQ   = ws + WS_Q;
    const unsigned char* wsIdx = ws + WS_IDX;

    // ---------------- Chunk loop: stage 128 gvfs, compute ------------------
#pragma unroll 1
    for (int k = 0; k < NCHUNK; ++k) {
        __syncthreads(); // previous chunk's LDS reads (and phase A) retired

        // stage: pieces 0..15 wt(i), 16..33 q(a), 34..49 idx(i); per-wave.
        for (int p = wv; p < 50; p += 8) {
            if (p < 16) {
                const unsigned char* src = wsWt + (size_t)p * (N_GVFS * HPG * 2)
                                                + (size_t)k * (CHUNK * HPG * 2);
                char* dst = (char*)wt_s + p * (CHUNK * HPG * 2);
                gll16(src + lane * 16, dst);
                gll16(src + 1024 + lane * 16, dst + 1024);
            } else if (p < 34) {
                const int a = p - 16;
                const unsigned char* src = wsQ + (size_t)a * (N_GVFS * HPG * 2)
                                               + (size_t)k * (CHUNK * HPG * 2);
                char* dst = (char*)q_s + a * (CHUNK * HPG * 2);
                gll16(src + lane * 16, dst);
                gll16(src + 1024 + lane * 16, dst + 1024);
            } else {
                const int i = p - 34;
                const unsigned char* src = wsIdx + (size_t)i * (N_GVFS * 2)
                                                 + (size_t)k * (CHUNK * 2);
                char* dst = (char*)idx_s + i * (CHUNK * 2);
                gll4(src + lane * 4, dst);
            }
        }
        __syncthreads(); // compiler drains vmcnt(0) before s_barrier -> staged data visible

        // ---- compute chunk: gvf g = k*CHUNK + s, rows 2h,2h+1 ----
        int jv[IPG];
#pragma unroll
        for (int i = 0; i < IPG; ++i) jv[i] = idx_s[i * CHUNK + s];

        float v0[HPG], v1[HPG];
#pragma unroll
        for (int hh = 0; hh < HPG; ++hh) { v0[hh] = 0.f; v1[hh] = 0.f; }

#pragma unroll
        for (int i = 0; i < IPG; ++i) {
            const unsigned int xp = *(const unsigned int*)((const char*)obs_t + jv[i] * 16 + h * 4);
            const float x0 = bf_lo(xp), x1 = bf_hi(xp);
            const uint4 wp = *(const uint4*)((const char*)wt_s + (size_t)(i * CHUNK + s) * 16);
            float wr[HPG];
            wr[0] = bf_lo(wp.x); wr[1] = bf_hi(wp.x);
            wr[2] = bf_lo(wp.y); wr[3] = bf_hi(wp.y);
            wr[4] = bf_lo(wp.z); wr[5] = bf_hi(wp.z);
            wr[6] = bf_lo(wp.w); wr[7] = bf_hi(wp.w);
#pragma unroll
            for (int hh = 0; hh < HPG; ++hh) {
                v0[hh] = fmaf(x0, wr[hh], v0[hh]);
                v1[hh] = fmaf(x1, wr[hh], v1[hh]);
            }
        }
#pragma unroll
        for (int hh = 0; hh < HPG; ++hh) {
            v0[hh] = fmaxf(v0[hh], 0.f);
            v1[hh] = fmaxf(v1[hh], 0.f);
        }

#pragma unroll
        for (int a = 0; a < N_ACT; ++a) {
            const uint4 qp = *(const uint4*)((const char*)q_s + (size_t)(a * CHUNK + s) * 16);
            float qr[HPG];
            qr[0] = bf_lo(qp.x); qr[1] = bf_hi(qp.x);
            qr[2] = bf_lo(qp.y); qr[3] = bf_hi(qp.y);
            qr[4] = bf_lo(qp.z); qr[5] = bf_hi(qp.z);
            qr[6] = bf_lo(qp.w); qr[7] = bf_hi(qp.w);
            float a0 = qacc[0][a], a1 = qacc[1][a];
#pragma unroll
            for (int hh = 0; hh < HPG; ++hh) {
                a0 = fmaf(v0[hh], qr[hh], a0);
                a1 = fmaf(v1[hh], qr[hh], a1);
            }
            qacc[0][a] = a0; qacc[1][a] = a1;
        }
    }

    // ---------------- Phase C: Q-head obs part, pure fp32 from global ------
#pragma unroll 1
    for (int jj = 0; jj < OBS_DIM / (CHUNK * 4); ++jj) { // 8
        const int j = (jj * CHUNK + s) * 4;
        const float4 o0 = *(const float4*)(obs + (size_t)(b0 + 2 * h) * OBS_DIM + j);
        const float4 o1 = *(const float4*)(obs + (size_t)(b0 + 2 * h + 1) * OBS_DIM + j);
#pragma unroll
        for (int a = 0; a < N_ACT; ++a) {
            const float4 q4 = *(const float4*)(qW + (size_t)a * TOTAL_FEAT + j);
            qacc[0][a] = fmaf(o0.x, q4.x, fmaf(o0.y, q4.y, fmaf(o0.z, q4.z, fmaf(o0.w, q4.w, qacc[0][a]))));
            qacc[1][a] = fmaf(o1.x, q4.x, fmaf(o1.y, q4.y, fmaf(o1.z, q4.z, fmaf(o1.w, q4.w, qacc[1][a]))));
        }
    }

    // ---------------- Phase D: wave shuffle reduce -> 144 outputs ----------
#pragma unroll
    for (int r = 0; r < 2; ++r)
#pragma unroll
        for (int a = 0; a < N_ACT; ++a) {
            float t = qacc[r][a];
#pragma unroll
            for (int m2 = 1; m2 < 64; m2 <<= 1) t += __shfl_xor(t, m2, 64);
            if (lane == 0) red2[wv][r][a] = t;
        }
    __syncthreads();
    if (tid < BT * N_ACT) { // 144
        const int row = tid / N_ACT, a = tid % N_ACT;
        const int w0 = (row >> 1) * 2, r = row & 1;
        out[(size_t)(b0 + row) * N_ACT + a] = red2[w0][r][a] + red2[w0 + 1][r][a];
    }
}

// ---------------------------------------------------------------------------
// Insurance fallback if ws_size is ever too small (slow but correct, no ws).
// ---------------------------------------------------------------------------
__global__ __launch_bounds__(256)
void fallback_kernel(const float* __restrict__ obs, const float* __restrict__ W,
                     const float* __restrict__ qW, const int* __restrict__ gidx,
                     float* __restrict__ out)
{
    const int b = blockIdx.x, t = threadIdx.x;
    float acc[N_ACT];
#pragma unroll
    for (int a = 0; a < N_ACT; ++a) acc[a] = 0.f;
    for (int g = t; g < N_GVFS; g += 256) {
        float v[HPG];
#pragma unroll
        for (int hh = 0; hh < HPG; ++hh) v[hh] = 0.f;
        for (int i = 0; i < IPG; ++i) {
            const float x = obs[(size_t)b * OBS_DIM + gidx[g * 16 + i]];
#pragma unroll
            for (int hh = 0; hh < HPG; ++hh)
                v[hh] = fmaf(x, W[g * 128 + hh * 16 + i], v[hh]);
        }
#pragma unroll
        for (int hh = 0; hh < HPG; ++hh) v[hh] = fmaxf(v[hh], 0.f);
#pragma unroll
        for (int a = 0; a < N_ACT; ++a) {
            float t2 = 0.f;
#pragma unroll
            for (int hh = 0; hh < HPG; ++hh)
                t2 = fmaf(v[hh], qW[(size_t)a * TOTAL_FEAT + OBS_DIM + g * 8 + hh], t2);
            acc[a] += t2;
        }
    }
    for (int j = t; j < OBS_DIM; j += 256) {
        const float x = obs[(size_t)b * OBS_DIM + j];
#pragma unroll
        for (int a = 0; a < N_ACT; ++a)
            acc[a] = fmaf(x, qW[(size_t)a * TOTAL_FEAT + j], acc[a]);
    }
    __shared__ float rr[4][N_ACT];
    const int lane = t & 63, w = t >> 6;
#pragma unroll
    for (int a = 0; a < N_ACT; ++a) {
        float x = acc[a];
#pragma unroll
        for (int m = 1; m < 64; m <<= 1) x += __shfl_xor(x, m, 64);
        if (lane == 0) rr[w][a] = x;
    }
    __syncthreads();
    if (t < N_ACT)
        out[(size_t)b * N_ACT + t] = rr[0][t] + rr[1][t] + rr[2][t] + rr[3][t];
}

// ---------------------------------------------------------------------------
extern "C" void kernel_launch(void* const* d_in, const int* in_sizes, int n_in,
                              void* d_out, int out_size, void* d_ws, size_t ws_size,
                              hipStream_t stream) {
    const float* obs  = (const float*)d_in[0];
    const float* gvfW = (const float*)d_in[1];
    const float* qW   = (const float*)d_in[2];
    const int*   gidx = (const int*)d_in[3];
    float* out = (float*)d_out;

    if (ws_size >= WS_NEED) {
        unsigned char* ws = (unsigned char*)d_ws;
        pack_wt_kernel<<<dim3(256), dim3(256), 0, stream>>>(gvfW, (unsigned short*)(ws + WS_WT));
        pack_q_kernel<<<dim3(288), dim3(256), 0, stream>>>(qW, (unsigned short*)(ws + WS_Q));
        pack_idx_kernel<<<dim3(256), dim3(256), 0, stream>>>(gidx, (unsigned short*)(ws + WS_IDX));
        fused_kernel<<<dim3(B_SZ / BT), dim3(NTHREADS), 0, stream>>>(obs, qW, ws, out);
    } else {
        fallback_kernel<<<dim3(B_SZ), dim3(256), 0, stream>>>(obs, gvfW, qW, gidx, out);
    }
}

// Round 7
// 193.424 us; speedup vs baseline: 2.1095x; 1.1590x over previous
//
#include <hip/hip_runtime.h>

#define B_SZ 2048
#define OBS_DIM 4096
#define N_GVFS 4096
#define IPG 16
#define HPG 8
#define N_ACT 18
#define TOTAL_FEAT (OBS_DIM + HPG * N_GVFS) /* 36864 */

#define BT 8                 /* batch rows per block */
#define NTHREADS 512         /* 4 row-pair groups x 128 gvf slots */
#define CHUNK 128            /* gvfs staged in LDS per step */
#define NCHUNK (N_GVFS / CHUNK)

/* workspace layout (bytes), all fp16-packed */
#define WS_WT 0u             /* u32 wt[pe 0..15][g 0..4095][hq 0..3]; pe=(ipair*2+hhalf) : 1,048,576 */
#define WS_Q 1048576u        /* u32 q [a 0..17][g 0..4095][hp 0..3]                      : 1,179,648 */
#define WS_IDX 2228224u      /* u16 idx[i 0..15][g 0..4095] = (j<<4)|((j>>3)&3)          :   131,072 */
#define WS_NEED 2359296u

typedef unsigned int u32;
typedef unsigned short u16;
// NOTE: __builtin_amdgcn_cvt_pkrtz / fdot2 use the __fp16 vector flavor --
// _Float16-based vectors are an incompatible type on this toolchain (round 6
// compile failure).
typedef __attribute__((ext_vector_type(2))) __fp16 h2;
union U32H2 { u32 u; h2 h; };

__device__ __forceinline__ u32 pk_f16(float a, float b) {
    U32H2 t; t.h = __builtin_amdgcn_cvt_pkrtz(a, b); return t.u;
}

// dot2: c += a.x*b.x + a.y*b.y on packed f16 (v_dot2_f32_f16, gfx906+).
#if __has_builtin(__builtin_amdgcn_fdot2)
__device__ __forceinline__ float fdot2(u32 a, u32 b, float c) {
    U32H2 x, y; x.u = a; y.u = b;
    return __builtin_amdgcn_fdot2(x.h, y.h, c, false);
}
#else
__device__ __forceinline__ float fdot2(u32 a, u32 b, float c) {
    U32H2 x, y; x.u = a; y.u = b;
    return fmaf((float)x.h.x, (float)y.h.x, fmaf((float)x.h.y, (float)y.h.y, c));
}
#endif

#if __has_builtin(__builtin_amdgcn_perm)
__device__ __forceinline__ u32 lo_pair(u32 A, u32 B) { return __builtin_amdgcn_perm(B, A, 0x05040100u); }
__device__ __forceinline__ u32 hi_pair(u32 A, u32 B) { return __builtin_amdgcn_perm(B, A, 0x07060302u); }
#else
__device__ __forceinline__ u32 lo_pair(u32 A, u32 B) { return (A & 0xFFFFu) | (B << 16); }
__device__ __forceinline__ u32 hi_pair(u32 A, u32 B) { return (A >> 16) | (B & 0xFFFF0000u); }
#endif

// async global->LDS (LDS dest = wave-uniform base + lane*size; src per-lane)
__device__ __forceinline__ void gll16(const void* g, void* l) {
    __builtin_amdgcn_global_load_lds(
        (const __attribute__((address_space(1))) unsigned int*)g,
        (__attribute__((address_space(3))) unsigned int*)l, 16, 0, 0);
}
__device__ __forceinline__ void gll4(const void* g, void* l) {
    __builtin_amdgcn_global_load_lds(
        (const __attribute__((address_space(1))) unsigned int*)g,
        (__attribute__((address_space(3))) unsigned int*)l, 4, 0, 0);
}

// ---------------------------------------------------------------------------
// Single merged pack kernel (round 5 spent ~60 us on 3 separate launches).
//  blocks [0,128)   : wt  -> u32[(pp*2+(h>>2))*4096 + g][h&3] = pk(W[g][h][2pp], W[g][h][2pp+1])
//  blocks [128,416) : q   -> u32[a*4096 + g][hp] = pk(q[a][4096+8g+2hp], ..+2hp+1)
//  blocks [416,672) : idx -> u16[i*4096 + g] = (j<<4)|((j>>3)&3)
// ---------------------------------------------------------------------------
__global__ __launch_bounds__(256)
void pack_all_kernel(const float* __restrict__ W, const float* __restrict__ qW,
                     const int* __restrict__ gidx, unsigned char* __restrict__ ws) {
    const int bid = blockIdx.x, t = threadIdx.x;
    if (bid < 128) {
        const int id = bid * 256 + t;        // (g,h): reads 16 consecutive floats
        const int g = id >> 3, hh = id & 7;
        const float* src = W + (size_t)g * 128 + hh * 16;
        float w[16];
#pragma unroll
        for (int q4 = 0; q4 < 4; ++q4) {
            const float4 f = *(const float4*)(src + q4 * 4);
            w[q4 * 4 + 0] = f.x; w[q4 * 4 + 1] = f.y; w[q4 * 4 + 2] = f.z; w[q4 * 4 + 3] = f.w;
        }
        u32* dst = (u32*)(ws + WS_WT);
#pragma unroll
        for (int pp = 0; pp < 8; ++pp) {
            const int pe = pp * 2 + (hh >> 2);
            dst[(size_t)(pe * 4096 + g) * 4 + (hh & 3)] = pk_f16(w[2 * pp], w[2 * pp + 1]);
        }
    } else if (bid < 416) {
        const int id = (bid - 128) * 256 + t; // 0..73727 : (a,g)
        const int a = id >> 12, g = id & 4095;
        const float* src = qW + (size_t)a * TOTAL_FEAT + OBS_DIM + (size_t)g * 8;
        const float4 f0 = *(const float4*)(src);
        const float4 f1 = *(const float4*)(src + 4);
        u32* dst = (u32*)(ws + WS_Q) + (size_t)(a * 4096 + g) * 4;
        dst[0] = pk_f16(f0.x, f0.y); dst[1] = pk_f16(f0.z, f0.w);
        dst[2] = pk_f16(f1.x, f1.y); dst[3] = pk_f16(f1.z, f1.w);
    } else {
        const int id = (bid - 416) * 256 + t; // 0..65535 : (i,g)
        const int i = id >> 12, g = id & 4095;
        const u32 j = (u32)gidx[g * 16 + i];
        ((u16*)(ws + WS_IDX))[(size_t)i * 4096 + g] = (u16)((j << 4) | ((j >> 3) & 3));
    }
}

// ---------------------------------------------------------------------------
// Fused kernel. Block = 8 batch rows, 512 threads = 4 row-pair groups x 128
// gvf slots. All packed data fp16; all hot math v_dot2_f32_f16 (2 MAC/instr,
// no unpacking). Obs column j = 16 B (8 rows f16), row-words XOR-permuted by
// j[4:3] so random gathers spread over all 32 banks (round 5: 8-way conflict).
// ---------------------------------------------------------------------------
__global__ __launch_bounds__(NTHREADS)
void fused_kernel(const float* __restrict__ obs,
                  const float* __restrict__ qW,
                  const unsigned char* __restrict__ ws,
                  float* __restrict__ out)
{
    __shared__ __align__(16) unsigned char lds[65536 + 32768 + 36864 + 4096 + 1152];
    unsigned char* const obs_c = lds;            // 65536: col j at j*16, word w = pair^swz
    unsigned char* const wt_c  = lds + 65536;    // 32768: [pe][s][hq]: b128 at (pe*128+s)*16
    unsigned char* const q_c   = lds + 98304;    // 36864: [a][s][hp]:  b128 at (a*128+s)*16
    unsigned char* const idx_c = lds + 135168;   //  4096: [i][s] u16
    float* const red2          = (float*)(lds + 139264); // [8 waves][2 rows][18]

    const int tid  = threadIdx.x;
    const int b0   = blockIdx.x * BT;
    const int lane = tid & 63;
    const int wv   = tid >> 6;          // wave 0..7
    const int h    = tid >> 7;          // row-pair group 0..3 -> rows 2h,2h+1
    const int s    = tid & (CHUNK - 1); // gvf slot 0..127

    // ---------------- Phase A: obs -> LDS fp16 columns, swizzled -----------
    // word (j, p) holds rows (2p, 2p+1) packed; stored at j*16 + (p^(j>>3&3))*4.
    for (int m = 0; m < 32; ++m) {
        const int id = tid + NTHREADS * m;  // 0..16383 = (p,j)
        const int j = id & 4095, p = id >> 12;
        const float a = obs[(size_t)(b0 + 2 * p) * OBS_DIM + j];
        const float b = obs[(size_t)(b0 + 2 * p + 1) * OBS_DIM + j];
        const int w = p ^ ((j >> 3) & 3);
        *(u32*)(obs_c + j * 16 + w * 4) = pk_f16(a, b);
    }

    float qacc[2][N_ACT];
#pragma unroll
    for (int r = 0; r < 2; ++r)
#pragma unroll
        for (int a = 0; a < N_ACT; ++a) qacc[r][a] = 0.f;

    const unsigned char* wsWt  = ws + WS_WT;
    const unsigned char* wsQ   = ws + WS_Q;
    const unsigned char* wsIdx = ws + WS_IDX;

    // ---------------- Chunk loop -------------------------------------------
#pragma unroll 1
    for (int k = 0; k < NCHUNK; ++k) {
        __syncthreads(); // prior chunk's LDS reads (and phase A) retired

        // 50 pieces: 16 wt (2KB), 18 q (2KB), 16 idx (256B); round-robin by wave
        for (int p = wv; p < 50; p += 8) {
            if (p < 16) {
                const unsigned char* src = wsWt + ((size_t)p * 4096 + k * CHUNK) * 16;
                unsigned char* dst = wt_c + p * 2048;
                gll16(src + lane * 16, dst);
                gll16(src + 1024 + lane * 16, dst + 1024);
            } else if (p < 34) {
                const int a = p - 16;
                const unsigned char* src = wsQ + ((size_t)a * 4096 + k * CHUNK) * 16;
                unsigned char* dst = q_c + a * 2048;
                gll16(src + lane * 16, dst);
                gll16(src + 1024 + lane * 16, dst + 1024);
            } else {
                const int i = p - 34;
                const unsigned char* src = wsIdx + ((size_t)i * 4096 + k * CHUNK) * 2;
                gll4(src + lane * 4, idx_c + i * 256);
            }
        }
        __syncthreads(); // vmcnt(0) drained before barrier -> staged data visible

        // ---- gather addresses (swizzle baked into staged idx) ----
        int ga[IPG];
#pragma unroll
        for (int i = 0; i < IPG; ++i) {
            const u32 t16 = *(const u16*)(idx_c + i * 256 + s * 2);
            ga[i] = (int)(t16 & 0xFFF0u) + ((((u32)h ^ t16) & 3u) << 2);
        }

        // ---- GVF MLP: 8 i-pairs, all dot2 ----
        float v0[HPG], v1[HPG];
#pragma unroll
        for (int hh = 0; hh < HPG; ++hh) { v0[hh] = 0.f; v1[hh] = 0.f; }

#pragma unroll
        for (int pp = 0; pp < 8; ++pp) {
            const u32 xA = *(const u32*)(obs_c + ga[2 * pp]);     // (r0,r1)@j_i
            const u32 xB = *(const u32*)(obs_c + ga[2 * pp + 1]); // (r0,r1)@j_{i+1}
            const u32 x0 = lo_pair(xA, xB);                       // (x_i, x_{i+1}) row0
            const u32 x1 = hi_pair(xA, xB);                       // row1
            const uint4 wA = *(const uint4*)(wt_c + ((pp * 2 + 0) * CHUNK + s) * 16); // h0..3
            const uint4 wB = *(const uint4*)(wt_c + ((pp * 2 + 1) * CHUNK + s) * 16); // h4..7
            v0[0] = fdot2(x0, wA.x, v0[0]); v1[0] = fdot2(x1, wA.x, v1[0]);
            v0[1] = fdot2(x0, wA.y, v0[1]); v1[1] = fdot2(x1, wA.y, v1[1]);
            v0[2] = fdot2(x0, wA.z, v0[2]); v1[2] = fdot2(x1, wA.z, v1[2]);
            v0[3] = fdot2(x0, wA.w, v0[3]); v1[3] = fdot2(x1, wA.w, v1[3]);
            v0[4] = fdot2(x0, wB.x, v0[4]); v1[4] = fdot2(x1, wB.x, v1[4]);
            v0[5] = fdot2(x0, wB.y, v0[5]); v1[5] = fdot2(x1, wB.y, v1[5]);
            v0[6] = fdot2(x0, wB.z, v0[6]); v1[6] = fdot2(x1, wB.z, v1[6]);
            v0[7] = fdot2(x0, wB.w, v0[7]); v1[7] = fdot2(x1, wB.w, v1[7]);
        }

        // relu + pack v into f16 h-pairs
        u32 vp0[4], vp1[4];
#pragma unroll
        for (int hp = 0; hp < 4; ++hp) {
            vp0[hp] = pk_f16(fmaxf(v0[2 * hp], 0.f), fmaxf(v0[2 * hp + 1], 0.f));
            vp1[hp] = pk_f16(fmaxf(v1[2 * hp], 0.f), fmaxf(v1[2 * hp + 1], 0.f));
        }

        // ---- Q head gvf part: per action one b128 + 8 dot2 ----
#pragma unroll
        for (int a = 0; a < N_ACT; ++a) {
            const uint4 qp = *(const uint4*)(q_c + (a * CHUNK + s) * 16);
            float a0 = qacc[0][a], a1 = qacc[1][a];
            a0 = fdot2(vp0[0], qp.x, a0); a1 = fdot2(vp1[0], qp.x, a1);
            a0 = fdot2(vp0[1], qp.y, a0); a1 = fdot2(vp1[1], qp.y, a1);
            a0 = fdot2(vp0[2], qp.z, a0); a1 = fdot2(vp1[2], qp.z, a1);
            a0 = fdot2(vp0[3], qp.w, a0); a1 = fdot2(vp1[3], qp.w, a1);
            qacc[0][a] = a0; qacc[1][a] = a1;
        }
    }

    // ---------------- Phase C: Q-head obs part, pure fp32 from global ------
#pragma unroll 1
    for (int jj = 0; jj < OBS_DIM / (CHUNK * 4); ++jj) { // 8
        const int j = (jj * CHUNK + s) * 4;
        const float4 o0 = *(const float4*)(obs + (size_t)(b0 + 2 * h) * OBS_DIM + j);
        const float4 o1 = *(const float4*)(obs + (size_t)(b0 + 2 * h + 1) * OBS_DIM + j);
#pragma unroll
        for (int a = 0; a < N_ACT; ++a) {
            const float4 q4 = *(const float4*)(qW + (size_t)a * TOTAL_FEAT + j);
            qacc[0][a] = fmaf(o0.x, q4.x, fmaf(o0.y, q4.y, fmaf(o0.z, q4.z, fmaf(o0.w, q4.w, qacc[0][a]))));
            qacc[1][a] = fmaf(o1.x, q4.x, fmaf(o1.y, q4.y, fmaf(o1.z, q4.z, fmaf(o1.w, q4.w, qacc[1][a]))));
        }
    }

    // ---------------- Phase D: wave shuffle reduce -> 144 outputs ----------
#pragma unroll
    for (int r = 0; r < 2; ++r)
#pragma unroll
        for (int a = 0; a < N_ACT; ++a) {
            float t = qacc[r][a];
#pragma unroll
            for (int m2 = 1; m2 < 64; m2 <<= 1) t += __shfl_xor(t, m2, 64);
            if (lane == 0) red2[(wv * 2 + r) * N_ACT + a] = t;
        }
    __syncthreads();
    if (tid < BT * N_ACT) { // 144
        const int row = tid / N_ACT, a = tid % N_ACT;
        const int w0 = (row >> 1) * 2, r = row & 1;
        out[(size_t)(b0 + row) * N_ACT + a] =
            red2[(w0 * 2 + r) * N_ACT + a] + red2[((w0 + 1) * 2 + r) * N_ACT + a];
    }
}

// ---------------------------------------------------------------------------
// Insurance fallback if ws_size is ever too small (slow but correct, no ws).
// ---------------------------------------------------------------------------
__global__ __launch_bounds__(256)
void fallback_kernel(const float* __restrict__ obs, const float* __restrict__ W,
                     const float* __restrict__ qW, const int* __restrict__ gidx,
                     float* __restrict__ out)
{
    const int b = blockIdx.x, t = threadIdx.x;
    float acc[N_ACT];
#pragma unroll
    for (int a = 0; a < N_ACT; ++a) acc[a] = 0.f;
    for (int g = t; g < N_GVFS; g += 256) {
        float v[HPG];
#pragma unroll
        for (int hh = 0; hh < HPG; ++hh) v[hh] = 0.f;
        for (int i = 0; i < IPG; ++i) {
            const float x = obs[(size_t)b * OBS_DIM + gidx[g * 16 + i]];
#pragma unroll
            for (int hh = 0; hh < HPG; ++hh)
                v[hh] = fmaf(x, W[g * 128 + hh * 16 + i], v[hh]);
        }
#pragma unroll
        for (int hh = 0; hh < HPG; ++hh) v[hh] = fmaxf(v[hh], 0.f);
#pragma unroll
        for (int a = 0; a < N_ACT; ++a) {
            float t2 = 0.f;
#pragma unroll
            for (int hh = 0; hh < HPG; ++hh)
                t2 = fmaf(v[hh], qW[(size_t)a * TOTAL_FEAT + OBS_DIM + g * 8 + hh], t2);
            acc[a] += t2;
        }
    }
    for (int j = t; j < OBS_DIM; j += 256) {
        const float x = obs[(size_t)b * OBS_DIM + j];
#pragma unroll
        for (int a = 0; a < N_ACT; ++a)
            acc[a] = fmaf(x, qW[(size_t)a * TOTAL_FEAT + j], acc[a]);
    }
    __shared__ float rr[4][N_ACT];
    const int lane = t & 63, w = t >> 6;
#pragma unroll
    for (int a = 0; a < N_ACT; ++a) {
        float x = acc[a];
#pragma unroll
        for (int m = 1; m < 64; m <<= 1) x += __shfl_xor(x, m, 64);
        if (lane == 0) rr[w][a] = x;
    }
    __syncthreads();
    if (t < N_ACT)
        out[(size_t)b * N_ACT + t] = rr[0][t] + rr[1][t] + rr[2][t] + rr[3][t];
}

// ---------------------------------------------------------------------------
extern "C" void kernel_launch(void* const* d_in, const int* in_sizes, int n_in,
                              void* d_out, int out_size, void* d_ws, size_t ws_size,
                              hipStream_t stream) {
    const float* obs  = (const float*)d_in[0];
    const float* gvfW = (const float*)d_in[1];
    const float* qW   = (const float*)d_in[2];
    const int*   gidx = (const int*)d_in[3];
    float* out = (float*)d_out;

    if (ws_size >= WS_NEED) {
        unsigned char* ws = (unsigned char*)d_ws;
        pack_all_kernel<<<dim3(672), dim3(256), 0, stream>>>(gvfW, qW, gidx, ws);
        fused_kernel<<<dim3(B_SZ / BT), dim3(NTHREADS), 0, stream>>>(obs, qW, ws, out);
    } else {
        fallback_kernel<<<dim3(B_SZ), dim3(256), 0, stream>>>(obs, gvfW, qW, gidx, out);
    }
}

// Round 8
// 184.842 us; speedup vs baseline: 2.2074x; 1.0464x over previous
//
#include <hip/hip_runtime.h>

#define B_SZ 2048
#define OBS_DIM 4096
#define N_GVFS 4096
#define IPG 16
#define HPG 8
#define N_ACT 18
#define TOTAL_FEAT (OBS_DIM + HPG * N_GVFS) /* 36864 */

#define BT 8                 /* batch rows per block */
#define NTHREADS 512         /* 8 waves; lane = hp*16 + sl, s = wave*16 + sl */
#define CHUNK 128            /* gvfs staged in LDS per step */
#define NCHUNK (N_GVFS / CHUNK)

/* workspace layout (bytes), all fp16-packed */
#define WS_WT 0u             /* u32 wt[pe 0..15][g 0..4095][hq 0..3]; pe=(ipair*2+hhalf) : 1,048,576 */
#define WS_Q 1048576u        /* u32 q [a 0..17][g 0..4095][hp 0..3]                      : 1,179,648 */
#define WS_IDX 2228224u      /* u16 idx[c 0..31][s 0..127][i 0..15] = (j<<4)|((j>>3)&3)  :   131,072 */
#define WS_NEED 2359296u

typedef unsigned int u32;
typedef unsigned short u16;
// __builtin_amdgcn_cvt_pkrtz / fdot2 use the __fp16 vector flavor (round 6).
typedef __attribute__((ext_vector_type(2))) __fp16 h2;
union U32H2 { u32 u; h2 h; };

__device__ __forceinline__ u32 pk_f16(float a, float b) {
    U32H2 t; t.h = __builtin_amdgcn_cvt_pkrtz(a, b); return t.u;
}

// dot2: c += a.x*b.x + a.y*b.y on packed f16 (v_dot2_f32_f16).
#if __has_builtin(__builtin_amdgcn_fdot2)
__device__ __forceinline__ float fdot2(u32 a, u32 b, float c) {
    U32H2 x, y; x.u = a; y.u = b;
    return __builtin_amdgcn_fdot2(x.h, y.h, c, false);
}
#else
__device__ __forceinline__ float fdot2(u32 a, u32 b, float c) {
    U32H2 x, y; x.u = a; y.u = b;
    return fmaf((float)x.h.x, (float)y.h.x, fmaf((float)x.h.y, (float)y.h.y, c));
}
#endif

#if __has_builtin(__builtin_amdgcn_perm)
__device__ __forceinline__ u32 lo_pair(u32 A, u32 B) { return __builtin_amdgcn_perm(B, A, 0x05040100u); }
__device__ __forceinline__ u32 hi_pair(u32 A, u32 B) { return __builtin_amdgcn_perm(B, A, 0x07060302u); }
#else
__device__ __forceinline__ u32 lo_pair(u32 A, u32 B) { return (A & 0xFFFFu) | (B << 16); }
__device__ __forceinline__ u32 hi_pair(u32 A, u32 B) { return (A >> 16) | (B & 0xFFFF0000u); }
#endif

// async global->LDS (LDS dest = wave-uniform base + lane*size; src per-lane)
__device__ __forceinline__ void gll16(const void* g, void* l) {
    __builtin_amdgcn_global_load_lds(
        (const __attribute__((address_space(1))) unsigned int*)g,
        (__attribute__((address_space(3))) unsigned int*)l, 16, 0, 0);
}

// ---------------------------------------------------------------------------
// Merged pack kernel.
//  blocks [0,128)   : wt  -> u32[(pp*2+(h>>2))*4096 + g][h&3] = pk(W[g][h][2pp], W[g][h][2pp+1])
//  blocks [128,416) : q   -> u32[a*4096 + g][hp] = pk(q[a][4096+8g+2hp], ..+2hp+1)
//  blocks [416,672) : idx -> u16[(g>>7)*2048 + (g&127)*16 + i] = (j<<4)|((j>>3)&3)
// ---------------------------------------------------------------------------
__global__ __launch_bounds__(256)
void pack_all_kernel(const float* __restrict__ W, const float* __restrict__ qW,
                     const int* __restrict__ gidx, unsigned char* __restrict__ ws) {
    const int bid = blockIdx.x, t = threadIdx.x;
    if (bid < 128) {
        const int id = bid * 256 + t;        // (g,h): reads 16 consecutive floats
        const int g = id >> 3, hh = id & 7;
        const float* src = W + (size_t)g * 128 + hh * 16;
        float w[16];
#pragma unroll
        for (int q4 = 0; q4 < 4; ++q4) {
            const float4 f = *(const float4*)(src + q4 * 4);
            w[q4 * 4 + 0] = f.x; w[q4 * 4 + 1] = f.y; w[q4 * 4 + 2] = f.z; w[q4 * 4 + 3] = f.w;
        }
        u32* dst = (u32*)(ws + WS_WT);
#pragma unroll
        for (int pp = 0; pp < 8; ++pp) {
            const int pe = pp * 2 + (hh >> 2);
            dst[(size_t)(pe * 4096 + g) * 4 + (hh & 3)] = pk_f16(w[2 * pp], w[2 * pp + 1]);
        }
    } else if (bid < 416) {
        const int id = (bid - 128) * 256 + t; // 0..73727 : (a,g)
        const int a = id >> 12, g = id & 4095;
        const float* src = qW + (size_t)a * TOTAL_FEAT + OBS_DIM + (size_t)g * 8;
        const float4 f0 = *(const float4*)(src);
        const float4 f1 = *(const float4*)(src + 4);
        u32* dst = (u32*)(ws + WS_Q) + (size_t)(a * 4096 + g) * 4;
        dst[0] = pk_f16(f0.x, f0.y); dst[1] = pk_f16(f0.z, f0.w);
        dst[2] = pk_f16(f1.x, f1.y); dst[3] = pk_f16(f1.z, f1.w);
    } else {
        const int id = (bid - 416) * 256 + t; // 0..65535 : (g,i)
        const int g = id >> 4, i = id & 15;
        const u32 j = (u32)gidx[g * 16 + i];
        ((u16*)(ws + WS_IDX))[(size_t)(g >> 7) * 2048 + (size_t)(g & 127) * 16 + i] =
            (u16)((j << 4) | ((j >> 3) & 3));
    }
}

// ---------------------------------------------------------------------------
// Fused kernel. Block = 8 batch rows, 512 threads = 8 waves.
// Lane mapping (round 8): hp = (lane>>4) row-pair, sl = lane&15;
// gvf slot s = wave*16 + sl. All 4 row-pair groups live INSIDE each wave ->
// every wt/q ds_read_b128 has only 16 distinct addresses (256 contiguous B,
// 4-way broadcast) instead of 64 (1024 B): LDS-pipe traffic for weights /4.
// Obs gathers: 16 random columns per wave-instr instead of 64 -> ~2-way.
// idx staged [s][i] and read as 2 x b128 per chunk (was 16 x u16).
// ---------------------------------------------------------------------------
__global__ __launch_bounds__(NTHREADS)
void fused_kernel(const float* __restrict__ obs,
                  const float* __restrict__ qW,
                  const unsigned char* __restrict__ ws,
                  float* __restrict__ out)
{
    __shared__ __align__(16) unsigned char lds[65536 + 32768 + 36864 + 4096 + 4608];
    unsigned char* const obs_c = lds;            // 65536: col j at j*16, word w = hp^swz
    unsigned char* const wt_c  = lds + 65536;    // 32768: [pe][s]: b128 at (pe*128+s)*16
    unsigned char* const q_c   = lds + 98304;    // 36864: [a][s]:  b128 at (a*128+s)*16
    unsigned char* const idx_c = lds + 135168;   //  4096: [s][i] u16, 32 B per s
    float* const red2          = (float*)(lds + 139264); // [8 wv][4 hp][2 r][18]

    const int tid  = threadIdx.x;
    const int b0   = blockIdx.x * BT;
    const int lane = tid & 63;
    const int wv   = tid >> 6;           // wave 0..7
    const int hp   = lane >> 4;          // row-pair 0..3 -> rows 2hp,2hp+1
    const int s    = wv * 16 + (lane & 15); // gvf slot 0..127

    // ---------------- Phase A: obs -> LDS fp16 columns, swizzled -----------
    // word (j, p) holds rows (2p, 2p+1) packed; stored at j*16 + (p^(j>>3&3))*4.
    for (int m = 0; m < 32; ++m) {
        const int id = tid + NTHREADS * m;  // 0..16383 = (p,j)
        const int j = id & 4095, p = id >> 12;
        const float a = obs[(size_t)(b0 + 2 * p) * OBS_DIM + j];
        const float b = obs[(size_t)(b0 + 2 * p + 1) * OBS_DIM + j];
        const int w = p ^ ((j >> 3) & 3);
        *(u32*)(obs_c + j * 16 + w * 4) = pk_f16(a, b);
    }

    float qacc[2][N_ACT];
#pragma unroll
    for (int r = 0; r < 2; ++r)
#pragma unroll
        for (int a = 0; a < N_ACT; ++a) qacc[r][a] = 0.f;

    const unsigned char* wsWt  = ws + WS_WT;
    const unsigned char* wsQ   = ws + WS_Q;
    const unsigned char* wsIdx = ws + WS_IDX;

    // ---------------- Chunk loop -------------------------------------------
#pragma unroll 1
    for (int k = 0; k < NCHUNK; ++k) {
        __syncthreads(); // prior chunk's LDS reads (and phase A) retired

        // 38 gll16 pieces (1 KB each): 16 wt x2KB, 18 q x2KB, 4 idx x1KB
        for (int p = wv; p < 38; p += 8) {
            if (p < 16) {
                const unsigned char* src = wsWt + ((size_t)p * 4096 + k * CHUNK) * 16;
                unsigned char* dst = wt_c + p * 2048;
                gll16(src + lane * 16, dst);
                gll16(src + 1024 + lane * 16, dst + 1024);
            } else if (p < 34) {
                const int a = p - 16;
                const unsigned char* src = wsQ + ((size_t)a * 4096 + k * CHUNK) * 16;
                unsigned char* dst = q_c + a * 2048;
                gll16(src + lane * 16, dst);
                gll16(src + 1024 + lane * 16, dst + 1024);
            } else {
                const int pi = p - 34;
                const unsigned char* src = wsIdx + (size_t)k * 4096 + pi * 1024;
                gll16(src + lane * 16, idx_c + pi * 1024);
            }
        }
        __syncthreads(); // vmcnt(0) drained before barrier -> staged data visible

        // ---- gather addresses: 2 b128 reads, extract 16 u16 ----
        const uint4 iw0 = *(const uint4*)(idx_c + s * 32);
        const uint4 iw1 = *(const uint4*)(idx_c + s * 32 + 16);
        const u32 iw[8] = {iw0.x, iw0.y, iw0.z, iw0.w, iw1.x, iw1.y, iw1.z, iw1.w};
        int ga[IPG];
#pragma unroll
        for (int q2 = 0; q2 < 8; ++q2) {
            const u32 lo = iw[q2] & 0xFFFFu;
            const u32 hi = iw[q2] >> 16;
            ga[2 * q2 + 0] = (int)(lo & 0xFFF0u) + ((((u32)hp ^ lo) & 3u) << 2);
            ga[2 * q2 + 1] = (int)(hi & 0xFFF0u) + ((((u32)hp ^ hi) & 3u) << 2);
        }

        // ---- GVF MLP: 8 i-pairs, all dot2 ----
        float v0[HPG], v1[HPG];
#pragma unroll
        for (int hh = 0; hh < HPG; ++hh) { v0[hh] = 0.f; v1[hh] = 0.f; }

#pragma unroll
        for (int pp = 0; pp < 8; ++pp) {
            const u32 xA = *(const u32*)(obs_c + ga[2 * pp]);     // (r0,r1)@j_i
            const u32 xB = *(const u32*)(obs_c + ga[2 * pp + 1]); // (r0,r1)@j_{i+1}
            const u32 x0 = lo_pair(xA, xB);                       // (x_i, x_{i+1}) row0
            const u32 x1 = hi_pair(xA, xB);                       // row1
            const uint4 wA = *(const uint4*)(wt_c + ((pp * 2 + 0) * CHUNK + s) * 16); // h0..3
            const uint4 wB = *(const uint4*)(wt_c + ((pp * 2 + 1) * CHUNK + s) * 16); // h4..7
            v0[0] = fdot2(x0, wA.x, v0[0]); v1[0] = fdot2(x1, wA.x, v1[0]);
            v0[1] = fdot2(x0, wA.y, v0[1]); v1[1] = fdot2(x1, wA.y, v1[1]);
            v0[2] = fdot2(x0, wA.z, v0[2]); v1[2] = fdot2(x1, wA.z, v1[2]);
            v0[3] = fdot2(x0, wA.w, v0[3]); v1[3] = fdot2(x1, wA.w, v1[3]);
            v0[4] = fdot2(x0, wB.x, v0[4]); v1[4] = fdot2(x1, wB.x, v1[4]);
            v0[5] = fdot2(x0, wB.y, v0[5]); v1[5] = fdot2(x1, wB.y, v1[5]);
            v0[6] = fdot2(x0, wB.z, v0[6]); v1[6] = fdot2(x1, wB.z, v1[6]);
            v0[7] = fdot2(x0, wB.w, v0[7]); v1[7] = fdot2(x1, wB.w, v1[7]);
        }

        // relu + pack v into f16 h-pairs
        u32 vp0[4], vp1[4];
#pragma unroll
        for (int hq = 0; hq < 4; ++hq) {
            vp0[hq] = pk_f16(fmaxf(v0[2 * hq], 0.f), fmaxf(v0[2 * hq + 1], 0.f));
            vp1[hq] = pk_f16(fmaxf(v1[2 * hq], 0.f), fmaxf(v1[2 * hq + 1], 0.f));
        }

        // ---- Q head gvf part: per action one b128 (broadcast) + 8 dot2 ----
#pragma unroll
        for (int a = 0; a < N_ACT; ++a) {
            const uint4 qp = *(const uint4*)(q_c + (a * CHUNK + s) * 16);
            float a0 = qacc[0][a], a1 = qacc[1][a];
            a0 = fdot2(vp0[0], qp.x, a0); a1 = fdot2(vp1[0], qp.x, a1);
            a0 = fdot2(vp0[1], qp.y, a0); a1 = fdot2(vp1[1], qp.y, a1);
            a0 = fdot2(vp0[2], qp.z, a0); a1 = fdot2(vp1[2], qp.z, a1);
            a0 = fdot2(vp0[3], qp.w, a0); a1 = fdot2(vp1[3], qp.w, a1);
            qacc[0][a] = a0; qacc[1][a] = a1;
        }
    }

    // ---------------- Phase C: Q-head obs part, pure fp32 from global ------
#pragma unroll 1
    for (int jj = 0; jj < OBS_DIM / (CHUNK * 4); ++jj) { // 8
        const int j = (jj * CHUNK + s) * 4;
        const float4 o0 = *(const float4*)(obs + (size_t)(b0 + 2 * hp) * OBS_DIM + j);
        const float4 o1 = *(const float4*)(obs + (size_t)(b0 + 2 * hp + 1) * OBS_DIM + j);
#pragma unroll
        for (int a = 0; a < N_ACT; ++a) {
            const float4 q4 = *(const float4*)(qW + (size_t)a * TOTAL_FEAT + j);
            qacc[0][a] = fmaf(o0.x, q4.x, fmaf(o0.y, q4.y, fmaf(o0.z, q4.z, fmaf(o0.w, q4.w, qacc[0][a]))));
            qacc[1][a] = fmaf(o1.x, q4.x, fmaf(o1.y, q4.y, fmaf(o1.z, q4.z, fmaf(o1.w, q4.w, qacc[1][a]))));
        }
    }

    // ---------------- Phase D: 16-lane group reduce -> 144 outputs ---------
    // Each hp group (16 lanes) holds one row-pair's partials within the wave.
#pragma unroll
    for (int r = 0; r < 2; ++r)
#pragma unroll
        for (int a = 0; a < N_ACT; ++a) {
            float t = qacc[r][a];
            t += __shfl_xor(t, 1, 64);
            t += __shfl_xor(t, 2, 64);
            t += __shfl_xor(t, 4, 64);
            t += __shfl_xor(t, 8, 64);
            if ((lane & 15) == 0)
                red2[((wv * 4 + hp) * 2 + r) * N_ACT + a] = t;
        }
    __syncthreads();
    if (tid < BT * N_ACT) { // 144
        const int row = tid / N_ACT, a = tid % N_ACT;
        const int hg = row >> 1, r = row & 1;
        float sum = 0.f;
#pragma unroll
        for (int w2 = 0; w2 < 8; ++w2)
            sum += red2[((w2 * 4 + hg) * 2 + r) * N_ACT + a];
        out[(size_t)(b0 + row) * N_ACT + a] = sum;
    }
}

// ---------------------------------------------------------------------------
// Insurance fallback if ws_size is ever too small (slow but correct, no ws).
// ---------------------------------------------------------------------------
__global__ __launch_bounds__(256)
void fallback_kernel(const float* __restrict__ obs, const float* __restrict__ W,
                     const float* __restrict__ qW, const int* __restrict__ gidx,
                     float* __restrict__ out)
{
    const int b = blockIdx.x, t = threadIdx.x;
    float acc[N_ACT];
#pragma unroll
    for (int a = 0; a < N_ACT; ++a) acc[a] = 0.f;
    for (int g = t; g < N_GVFS; g += 256) {
        float v[HPG];
#pragma unroll
        for (int hh = 0; hh < HPG; ++hh) v[hh] = 0.f;
        for (int i = 0; i < IPG; ++i) {
            const float x = obs[(size_t)b * OBS_DIM + gidx[g * 16 + i]];
#pragma unroll
            for (int hh = 0; hh < HPG; ++hh)
                v[hh] = fmaf(x, W[g * 128 + hh * 16 + i], v[hh]);
        }
#pragma unroll
        for (int hh = 0; hh < HPG; ++hh) v[hh] = fmaxf(v[hh], 0.f);
#pragma unroll
        for (int a = 0; a < N_ACT; ++a) {
            float t2 = 0.f;
#pragma unroll
            for (int hh = 0; hh < HPG; ++hh)
                t2 = fmaf(v[hh], qW[(size_t)a * TOTAL_FEAT + OBS_DIM + g * 8 + hh], t2);
            acc[a] += t2;
        }
    }
    for (int j = t; j < OBS_DIM; j += 256) {
        const float x = obs[(size_t)b * OBS_DIM + j];
#pragma unroll
        for (int a = 0; a < N_ACT; ++a)
            acc[a] = fmaf(x, qW[(size_t)a * TOTAL_FEAT + j], acc[a]);
    }
    __shared__ float rr[4][N_ACT];
    const int lane = t & 63, w = t >> 6;
#pragma unroll
    for (int a = 0; a < N_ACT; ++a) {
        float x = acc[a];
#pragma unroll
        for (int m = 1; m < 64; m <<= 1) x += __shfl_xor(x, m, 64);
        if (lane == 0) rr[w][a] = x;
    }
    __syncthreads();
    if (t < N_ACT)
        out[(size_t)b * N_ACT + t] = rr[0][t] + rr[1][t] + rr[2][t] + rr[3][t];
}

// ---------------------------------------------------------------------------
extern "C" void kernel_launch(void* const* d_in, const int* in_sizes, int n_in,
                              void* d_out, int out_size, void* d_ws, size_t ws_size,
                              hipStream_t stream) {
    const float* obs  = (const float*)d_in[0];
    const float* gvfW = (const float*)d_in[1];
    const float* qW   = (const float*)d_in[2];
    const int*   gidx = (const int*)d_in[3];
    float* out = (float*)d_out;

    if (ws_size >= WS_NEED) {
        unsigned char* ws = (unsigned char*)d_ws;
        pack_all_kernel<<<dim3(672), dim3(256), 0, stream>>>(gvfW, qW, gidx, ws);
        fused_kernel<<<dim3(B_SZ / BT), dim3(NTHREADS), 0, stream>>>(obs, qW, ws, out);
    } else {
        fallback_kernel<<<dim3(B_SZ), dim3(256), 0, stream>>>(obs, gvfW, qW, gidx, out);
    }
}